// Round 1
// baseline (204.194 us; speedup 1.0000x reference)
//
#include <hip/hip_runtime.h>
#include <cfloat>
#include <cmath>

#define F_   8
#define H_   24
#define W_   24
#define NTOK (F_*H_*W_)     // 4608
#define NSEQ (NTOK+1)       // 4609
#define NHEADS 8
#define DH   64
#define DIM  512
#define QKVC 1536           // q(512) | k(512) | v(512)
#define NNB  28             // 1 BOS + 27 neighbors
#define SCALEF 0.125f       // 64^-0.5

// ---------------------------------------------------------------------------
// GEMM 1: qkv[NSEQ x 1536] = x[NSEQ x 512] @ [w_q (512x512) | w_kv (512x1024)]
// 64x64 tile, 256 threads, 4x4 per thread, f32.
// ---------------------------------------------------------------------------
__global__ __launch_bounds__(256) void gemm_qkv_k(
    const float* __restrict__ x,
    const float* __restrict__ wq,
    const float* __restrict__ wkv,
    float* __restrict__ qkv)
{
    const int bm = blockIdx.y, bn = blockIdx.x;
    const int tid = threadIdx.x;
    const int ty = tid >> 4, tx = tid & 15;
    __shared__ float As[16][68];
    __shared__ float Bs[16][68];
    float acc[4][4] = {};
    const int row0 = bm * 64, col0 = bn * 64;

    const float* B; int ldb; int bcol;
    if (col0 < 512) { B = wq;  ldb = 512;  bcol = col0; }
    else            { B = wkv; ldb = 1024; bcol = col0 - 512; }

    for (int k0 = 0; k0 < DIM; k0 += 16) {
        // A tile 64x16 (transposed into As[k][m])
        {
            int ml = tid >> 2, kq = (tid & 3) << 2;
            int m = row0 + ml;
            float4 av = make_float4(0.f, 0.f, 0.f, 0.f);
            if (m < NSEQ) av = *reinterpret_cast<const float4*>(&x[(size_t)m * DIM + k0 + kq]);
            As[kq + 0][ml] = av.x; As[kq + 1][ml] = av.y;
            As[kq + 2][ml] = av.z; As[kq + 3][ml] = av.w;
        }
        // B tile 16x64
        {
            int kl = tid >> 4, nq = (tid & 15) << 2;
            float4 bv = *reinterpret_cast<const float4*>(&B[(size_t)(k0 + kl) * ldb + bcol + nq]);
            *reinterpret_cast<float4*>(&Bs[kl][nq]) = bv;
        }
        __syncthreads();
        #pragma unroll
        for (int kk = 0; kk < 16; ++kk) {
            float a[4], b[4];
            #pragma unroll
            for (int i = 0; i < 4; ++i) a[i] = As[kk][ty * 4 + i];
            #pragma unroll
            for (int j = 0; j < 4; ++j) b[j] = Bs[kk][tx * 4 + j];
            #pragma unroll
            for (int i = 0; i < 4; ++i)
                #pragma unroll
                for (int j = 0; j < 4; ++j)
                    acc[i][j] += a[i] * b[j];
        }
        __syncthreads();
    }
    #pragma unroll
    for (int i = 0; i < 4; ++i) {
        int m = row0 + ty * 4 + i;
        if (m < NSEQ) {
            #pragma unroll
            for (int j = 0; j < 4; ++j)
                qkv[(size_t)m * QKVC + col0 + tx * 4 + j] = acc[i][j];
        }
    }
}

// ---------------------------------------------------------------------------
// Attention: one block (256 thr) per token i in [0, 4608).
// qkv row r: q at +0, k at +512, v at +1024 (col = h*64 + d).
// Token i uses projected row i+1; BOS is row 0, attended by all (col j=0).
// Neighbor j in 1..27: offsets (dt,dy,dx) in {-1,0,1}^3, masked if out of
// volume or neighbor token id u > i (causal). Softmax over 28, talking-heads
// mix (w_talk[g][h]), PV, write out_heads row i+1. Block 0 writes row 0 = v[0].
// ---------------------------------------------------------------------------
__global__ __launch_bounds__(256) void attn_k(
    const float* __restrict__ qkv,
    const float* __restrict__ wtalk,
    float* __restrict__ outh)
{
    const int i = blockIdx.x;
    const int tid = threadIdx.x;

    __shared__ float q_s[DIM];
    __shared__ float sim_s[NHEADS][NNB];
    __shared__ float p_s[NHEADS][NNB];
    __shared__ int   row_s[NNB];
    __shared__ float wt_s[64];

    const int t   = i / (H_ * W_);
    const int rem = i % (H_ * W_);
    const int yy  = rem / W_;
    const int xx  = rem % W_;

    q_s[tid]       = qkv[(size_t)(i + 1) * QKVC + tid];
    q_s[tid + 256] = qkv[(size_t)(i + 1) * QKVC + 256 + tid];
    if (tid < 64) wt_s[tid] = wtalk[tid];
    if (tid < NNB) {
        int row;
        if (tid == 0) {
            row = 0;                       // BOS, never masked
        } else {
            int e = tid - 1;
            int dt = e / 9 - 1, dy = (e / 3) % 3 - 1, dx = e % 3 - 1;
            int nt = t + dt, ny = yy + dy, nx = xx + dx;
            bool valid = (nt >= 0 && nt < F_ && ny >= 0 && ny < H_ && nx >= 0 && nx < W_);
            int u = (nt * H_ + ny) * W_ + nx;
            bool masked = (!valid) || (u > i);
            row = masked ? -1 : (u + 1);
        }
        row_s[tid] = row;
    }
    __syncthreads();

    // sims: 224 (h,j) dot products of length 64
    if (tid < NHEADS * NNB) {
        int h = tid / NNB, j = tid % NNB;
        int row = row_s[j];
        float s;
        if (row < 0) {
            s = -FLT_MAX;
        } else {
            const float* kp = &qkv[(size_t)row * QKVC + 512 + h * 64];
            const float* qp = &q_s[h * 64];
            float acc = 0.f;
            #pragma unroll
            for (int d = 0; d < 64; ++d) acc += qp[d] * kp[d];
            s = acc * SCALEF;
        }
        sim_s[h][j] = s;
    }
    __syncthreads();

    // softmax per head (8 lanes serial over 28)
    if (tid < NHEADS) {
        int h = tid;
        float mx = -FLT_MAX;
        #pragma unroll
        for (int j = 0; j < NNB; ++j) mx = fmaxf(mx, sim_s[h][j]);
        float tmp[NNB];
        float sum = 0.f;
        #pragma unroll
        for (int j = 0; j < NNB; ++j) {
            float sv = sim_s[h][j];
            float e = (sv == -FLT_MAX) ? 0.f : expf(sv - mx);
            tmp[j] = e; sum += e;
        }
        float inv = 1.f / sum;
        #pragma unroll
        for (int j = 0; j < NNB; ++j) sim_s[h][j] = tmp[j] * inv;
    }
    __syncthreads();

    // talking heads: p[g][j] = sum_h wt[g][h] * attn[h][j]
    if (tid < NHEADS * NNB) {
        int g = tid / NNB, j = tid % NNB;
        float acc = 0.f;
        #pragma unroll
        for (int h = 0; h < NHEADS; ++h) acc += wt_s[g * 8 + h] * sim_s[h][j];
        p_s[g][j] = acc;
    }
    __syncthreads();

    // PV: 512 outputs, 2 per thread
    #pragma unroll
    for (int o = 0; o < 2; ++o) {
        int idx = tid + o * 256;
        int g = idx >> 6, d = idx & 63;
        float acc = 0.f;
        #pragma unroll
        for (int j = 0; j < NNB; ++j) {
            int row = row_s[j];
            if (row >= 0) acc += p_s[g][j] * qkv[(size_t)row * QKVC + 1024 + g * 64 + d];
        }
        outh[(size_t)(i + 1) * DIM + idx] = acc;
    }

    if (i == 0) {
        // out row 0 = v row 0 (v_bos concatenated over heads)
        outh[tid]       = qkv[1024 + tid];
        outh[tid + 256] = qkv[1024 + 256 + tid];
    }
}

// ---------------------------------------------------------------------------
// GEMM 2: out[NSEQ x 512] = outh[NSEQ x 512] @ w_out[512 x 512] + b_out
// ---------------------------------------------------------------------------
__global__ __launch_bounds__(256) void gemm_out_k(
    const float* __restrict__ A,
    const float* __restrict__ B,
    const float* __restrict__ bias,
    float* __restrict__ C)
{
    const int bm = blockIdx.y, bn = blockIdx.x;
    const int tid = threadIdx.x;
    const int ty = tid >> 4, tx = tid & 15;
    __shared__ float As[16][68];
    __shared__ float Bs[16][68];
    float acc[4][4] = {};
    const int row0 = bm * 64, col0 = bn * 64;

    for (int k0 = 0; k0 < DIM; k0 += 16) {
        {
            int ml = tid >> 2, kq = (tid & 3) << 2;
            int m = row0 + ml;
            float4 av = make_float4(0.f, 0.f, 0.f, 0.f);
            if (m < NSEQ) av = *reinterpret_cast<const float4*>(&A[(size_t)m * DIM + k0 + kq]);
            As[kq + 0][ml] = av.x; As[kq + 1][ml] = av.y;
            As[kq + 2][ml] = av.z; As[kq + 3][ml] = av.w;
        }
        {
            int kl = tid >> 4, nq = (tid & 15) << 2;
            float4 bv = *reinterpret_cast<const float4*>(&B[(size_t)(k0 + kl) * DIM + col0 + nq]);
            *reinterpret_cast<float4*>(&Bs[kl][nq]) = bv;
        }
        __syncthreads();
        #pragma unroll
        for (int kk = 0; kk < 16; ++kk) {
            float a[4], b[4];
            #pragma unroll
            for (int i = 0; i < 4; ++i) a[i] = As[kk][ty * 4 + i];
            #pragma unroll
            for (int j = 0; j < 4; ++j) b[j] = Bs[kk][tx * 4 + j];
            #pragma unroll
            for (int i = 0; i < 4; ++i)
                #pragma unroll
                for (int j = 0; j < 4; ++j)
                    acc[i][j] += a[i] * b[j];
        }
        __syncthreads();
    }
    #pragma unroll
    for (int i = 0; i < 4; ++i) {
        int m = row0 + ty * 4 + i;
        if (m < NSEQ) {
            #pragma unroll
            for (int j = 0; j < 4; ++j) {
                int c = col0 + tx * 4 + j;
                C[(size_t)m * DIM + c] = acc[i][j] + bias[c];
            }
        }
    }
}

extern "C" void kernel_launch(void* const* d_in, const int* in_sizes, int n_in,
                              void* d_out, int out_size, void* d_ws, size_t ws_size,
                              hipStream_t stream) {
    const float* x     = (const float*)d_in[0];
    const float* wq    = (const float*)d_in[1];
    const float* wkv   = (const float*)d_in[2];
    const float* wtalk = (const float*)d_in[3];
    const float* wout  = (const float*)d_in[4];
    const float* bout  = (const float*)d_in[5];
    float* out = (float*)d_out;

    float* qkv  = (float*)d_ws;                          // NSEQ*1536 f32
    float* outh = qkv + (size_t)NSEQ * QKVC;             // NSEQ*512  f32

    dim3 blk(256);
    // QKV projection: N=1536 -> 24 col tiles, M=4609 -> 73 row tiles
    gemm_qkv_k<<<dim3(24, 73), blk, 0, stream>>>(x, wq, wkv, qkv);
    // Attention: one block per token
    attn_k<<<dim3(NTOK), blk, 0, stream>>>(qkv, wtalk, outh);
    // Output projection: N=512 -> 8 col tiles
    gemm_out_k<<<dim3(8, 73), blk, 0, stream>>>(outh, wout, bout, out);
}

// Round 2
// 90.839 us; speedup vs baseline: 2.2479x; 2.2479x over previous
//
#include <hip/hip_runtime.h>
#include <cfloat>
#include <cmath>

#define F_   8
#define H_   24
#define W_   24
#define NTOK 4608
#define NSEQ 4609
#define MPAD 4736           // 37 * 128
#define DIM  512
#define QKVC 1536           // q | k | v
#define NNB  28
#define SCALEF 0.125f

typedef unsigned short ushort_t;
typedef __attribute__((ext_vector_type(8))) short short8v;
typedef __attribute__((ext_vector_type(8))) unsigned short ushort8v;
typedef __attribute__((ext_vector_type(4))) unsigned short ushort4v;
typedef __attribute__((ext_vector_type(4))) float floatx4;

typedef const __attribute__((address_space(1))) unsigned int guint_t;
typedef __attribute__((address_space(3))) unsigned int luint_t;

__device__ __forceinline__ float bf2f(unsigned short u) {
    return __uint_as_float(((unsigned)u) << 16);
}
__device__ __forceinline__ unsigned short f2bf(float f) {
    unsigned u = __float_as_uint(f);
    unsigned r = (u + 0x7FFFu + ((u >> 16) & 1u)) >> 16;
    return (unsigned short)r;
}

// ---------------------------------------------------------------------------
// Fused conversion: x(f32)->xb(bf16, zero-padded rows to MPAD),
// [w_q | w_kv] -> w_catT (bf16, transposed to [1536][512]),
// w_out -> w_outT (bf16, transposed to [512][512]).
// ---------------------------------------------------------------------------
#define XQ   (MPAD * DIM / 4)      // 606208 quads
#define WCQ  (QKVC * DIM / 4)      // 196608
#define WOQ  (DIM * DIM / 4)       // 65536
#define CONV_BLOCKS ((XQ + WCQ + WOQ) / 256)   // 3392

__global__ __launch_bounds__(256) void conv_k(
    const float* __restrict__ x, const float* __restrict__ wq,
    const float* __restrict__ wkv, const float* __restrict__ wout,
    ushort_t* __restrict__ xb, ushort_t* __restrict__ wcatT,
    ushort_t* __restrict__ woutT)
{
    int id = blockIdx.x * 256 + threadIdx.x;
    if (id < XQ) {
        int e = id * 4;
        int row = e >> 9;
        float4 v = make_float4(0.f, 0.f, 0.f, 0.f);
        if (row < NSEQ) v = *reinterpret_cast<const float4*>(&x[e]);
        ushort4v o = { f2bf(v.x), f2bf(v.y), f2bf(v.z), f2bf(v.w) };
        *reinterpret_cast<ushort4v*>(&xb[e]) = o;
    } else if (id < XQ + WCQ) {
        int e = (id - XQ) * 4;
        int n = e >> 9, k0 = e & 511;
        ushort4v o;
        #pragma unroll
        for (int i2 = 0; i2 < 4; ++i2) {
            float v = (n < 512) ? wq[(size_t)(k0 + i2) * 512 + n]
                                : wkv[(size_t)(k0 + i2) * 1024 + (n - 512)];
            o[i2] = f2bf(v);
        }
        *reinterpret_cast<ushort4v*>(&wcatT[(size_t)n * 512 + k0]) = o;
    } else {
        int e = (id - XQ - WCQ) * 4;
        int n = e >> 9, k0 = e & 511;
        ushort4v o;
        #pragma unroll
        for (int i2 = 0; i2 < 4; ++i2)
            o[i2] = f2bf(wout[(size_t)(k0 + i2) * 512 + n]);
        *reinterpret_cast<ushort4v*>(&woutT[(size_t)n * 512 + k0]) = o;
    }
}

// ---------------------------------------------------------------------------
// bf16 MFMA GEMM: C[M x N] = A[M x 512] * B[512 x N], B given transposed
// (BT[N][512]). 128x128 tile, BK=64, 4 waves, 16x16x32 MFMA, 4x4 frags/wave.
// global_load_lds width-16 staging, XOR slot swizzle (slot ^= row&7) applied
// on BOTH the pre-swizzled global source and the ds_read address (dest linear).
// F32OUT=false: bf16 store, no guard (C padded). F32OUT=true: f32 + bias,
// row < NSEQ guard.
// ---------------------------------------------------------------------------
template<bool F32OUT>
__global__ __launch_bounds__(256, 2) void gemm_k(
    const ushort_t* __restrict__ A,    // [MPAD][512] bf16
    const ushort_t* __restrict__ BT,   // [N][512] bf16
    const float* __restrict__ bias,
    void* __restrict__ Cv, int ldc)
{
    __shared__ ushort_t sA[128 * 64];
    __shared__ ushort_t sB[128 * 64];
    const int tid = threadIdx.x;
    const int row0 = blockIdx.y * 128, col0 = blockIdx.x * 128;
    const int wid = tid >> 6, lane = tid & 63;
    const int wr = wid >> 1, wc = wid & 1;
    const int l15 = lane & 15, kp = lane >> 4;

    floatx4 acc[4][4];
    #pragma unroll
    for (int m = 0; m < 4; ++m)
        #pragma unroll
        for (int n = 0; n < 4; ++n)
            acc[m][n] = (floatx4){0.f, 0.f, 0.f, 0.f};

    const ushort_t* Abase = A + (size_t)row0 * 512;
    const ushort_t* Bbase = BT + (size_t)col0 * 512;

    for (int kt = 0; kt < 8; ++kt) {
        const int k0 = kt * 64;
        #pragma unroll
        for (int rnd = 0; rnd < 4; ++rnd) {
            int r = rnd * 32 + (tid >> 3);
            int gs = (tid & 7) ^ (r & 7);
            __builtin_amdgcn_global_load_lds(
                (guint_t*)(Abase + (size_t)r * 512 + k0 + gs * 8),
                (luint_t*)(sA + r * 64 + (tid & 7) * 8), 16, 0, 0);
        }
        #pragma unroll
        for (int rnd = 0; rnd < 4; ++rnd) {
            int r = rnd * 32 + (tid >> 3);
            int gs = (tid & 7) ^ (r & 7);
            __builtin_amdgcn_global_load_lds(
                (guint_t*)(Bbase + (size_t)r * 512 + k0 + gs * 8),
                (luint_t*)(sB + r * 64 + (tid & 7) * 8), 16, 0, 0);
        }
        __syncthreads();

        short8v af[4][2], bfr[4][2];
        #pragma unroll
        for (int m = 0; m < 4; ++m) {
            int r = wr * 64 + m * 16 + l15;
            #pragma unroll
            for (int kk = 0; kk < 2; ++kk) {
                int slot = kk * 4 + kp;
                af[m][kk] = *(const short8v*)&sA[r * 64 + ((slot ^ (r & 7)) << 3)];
            }
        }
        #pragma unroll
        for (int n = 0; n < 4; ++n) {
            int r = wc * 64 + n * 16 + l15;
            #pragma unroll
            for (int kk = 0; kk < 2; ++kk) {
                int slot = kk * 4 + kp;
                bfr[n][kk] = *(const short8v*)&sB[r * 64 + ((slot ^ (r & 7)) << 3)];
            }
        }
        #pragma unroll
        for (int kk = 0; kk < 2; ++kk)
            #pragma unroll
            for (int m = 0; m < 4; ++m)
                #pragma unroll
                for (int n = 0; n < 4; ++n)
                    acc[m][n] = __builtin_amdgcn_mfma_f32_16x16x32_bf16(
                        af[m][kk], bfr[n][kk], acc[m][n], 0, 0, 0);
        __syncthreads();
    }

    if (!F32OUT) {
        ushort_t* C = (ushort_t*)Cv;
        #pragma unroll
        for (int m = 0; m < 4; ++m) {
            int rb = row0 + wr * 64 + m * 16 + kp * 4;
            #pragma unroll
            for (int n = 0; n < 4; ++n) {
                int col = col0 + wc * 64 + n * 16 + l15;
                #pragma unroll
                for (int q = 0; q < 4; ++q)
                    C[(size_t)(rb + q) * ldc + col] = f2bf(acc[m][n][q]);
            }
        }
    } else {
        float* C = (float*)Cv;
        #pragma unroll
        for (int m = 0; m < 4; ++m) {
            int rb = row0 + wr * 64 + m * 16 + kp * 4;
            #pragma unroll
            for (int n = 0; n < 4; ++n) {
                int col = col0 + wc * 64 + n * 16 + l15;
                float bv = bias[col];
                #pragma unroll
                for (int q = 0; q < 4; ++q)
                    if (rb + q < NSEQ)
                        C[(size_t)(rb + q) * ldc + col] = acc[m][n][q] + bv;
            }
        }
    }
}

// ---------------------------------------------------------------------------
// Attention: one block (256 thr) per token i. qkv is bf16 [MPAD][1536]
// (q | k | v per row). Computes the 28-neighbor causal attention with
// talking-heads mixing, writes bf16 outh row i+1; block 0 also writes
// row 0 = v[BOS].
// ---------------------------------------------------------------------------
__global__ __launch_bounds__(256) void attn_k(
    const ushort_t* __restrict__ qkv,
    const float* __restrict__ wtalk,
    ushort_t* __restrict__ outh)
{
    const int i = blockIdx.x;
    const int tid = threadIdx.x;

    __shared__ float q_s[DIM];
    __shared__ float sim_s[8][NNB];
    __shared__ float p_s[8][NNB];
    __shared__ int   row_s[NNB];
    __shared__ float wt_s[64];

    const int t   = i / (H_ * W_);
    const int rem = i % (H_ * W_);
    const int yy  = rem / W_;
    const int xx  = rem % W_;

    {
        const ushort_t* qp = &qkv[(size_t)(i + 1) * QKVC + tid * 2];
        q_s[tid * 2]     = bf2f(qp[0]);
        q_s[tid * 2 + 1] = bf2f(qp[1]);
    }
    if (tid < 64) wt_s[tid] = wtalk[tid];
    if (tid < NNB) {
        int row;
        if (tid == 0) {
            row = 0;
        } else {
            int e = tid - 1;
            int dt = e / 9 - 1, dy = (e / 3) % 3 - 1, dx = e % 3 - 1;
            int nt = t + dt, ny = yy + dy, nx = xx + dx;
            bool valid = (nt >= 0 && nt < F_ && ny >= 0 && ny < H_ && nx >= 0 && nx < W_);
            int u = (nt * H_ + ny) * W_ + nx;
            bool masked = (!valid) || (u > i);
            row = masked ? -1 : (u + 1);
        }
        row_s[tid] = row;
    }
    __syncthreads();

    if (tid < 8 * NNB) {
        int h = tid / NNB, j = tid % NNB;
        int row = row_s[j];
        float s = -FLT_MAX;
        if (row >= 0) {
            const ushort_t* kp = &qkv[(size_t)row * QKVC + 512 + h * 64];
            const float* qp = &q_s[h * 64];
            float acc = 0.f;
            #pragma unroll
            for (int c = 0; c < 8; ++c) {
                ushort8v kv = *(const ushort8v*)&kp[c * 8];
                #pragma unroll
                for (int e = 0; e < 8; ++e) acc += qp[c * 8 + e] * bf2f(kv[e]);
            }
            s = acc * SCALEF;
        }
        sim_s[h][j] = s;
    }
    __syncthreads();

    if (tid < 8) {
        int h = tid;
        float mx = -FLT_MAX;
        #pragma unroll
        for (int j = 0; j < NNB; ++j) mx = fmaxf(mx, sim_s[h][j]);
        float tmp[NNB];
        float sum = 0.f;
        #pragma unroll
        for (int j = 0; j < NNB; ++j) {
            float sv = sim_s[h][j];
            float e = (sv == -FLT_MAX) ? 0.f : __expf(sv - mx);
            tmp[j] = e; sum += e;
        }
        float inv = 1.f / sum;
        #pragma unroll
        for (int j = 0; j < NNB; ++j) sim_s[h][j] = tmp[j] * inv;
    }
    __syncthreads();

    if (tid < 8 * NNB) {
        int g = tid / NNB, j = tid % NNB;
        float acc = 0.f;
        #pragma unroll
        for (int h = 0; h < 8; ++h) acc += wt_s[g * 8 + h] * sim_s[h][j];
        p_s[g][j] = acc;
    }
    __syncthreads();

    #pragma unroll
    for (int o = 0; o < 2; ++o) {
        int idx = tid + o * 256;
        int g = idx >> 6, d = idx & 63;
        float acc = 0.f;
        #pragma unroll
        for (int j = 0; j < NNB; ++j) {
            int row = row_s[j];
            if (row >= 0)
                acc += p_s[g][j] * bf2f(qkv[(size_t)row * QKVC + 1024 + g * 64 + d]);
        }
        outh[(size_t)(i + 1) * DIM + idx] = f2bf(acc);
    }

    if (i == 0) {
        outh[tid]       = qkv[1024 + tid];
        outh[tid + 256] = qkv[1024 + 256 + tid];
    }
}

extern "C" void kernel_launch(void* const* d_in, const int* in_sizes, int n_in,
                              void* d_out, int out_size, void* d_ws, size_t ws_size,
                              hipStream_t stream) {
    const float* x     = (const float*)d_in[0];
    const float* wq    = (const float*)d_in[1];
    const float* wkv   = (const float*)d_in[2];
    const float* wtalk = (const float*)d_in[3];
    const float* wout  = (const float*)d_in[4];
    const float* bout  = (const float*)d_in[5];
    float* out = (float*)d_out;

    ushort_t* xb    = (ushort_t*)d_ws;                    // MPAD*512 bf16
    ushort_t* wcatT = xb    + (size_t)MPAD * 512;         // 1536*512
    ushort_t* woutT = wcatT + (size_t)QKVC * 512;         // 512*512
    ushort_t* qkv   = woutT + (size_t)512 * 512;          // MPAD*1536
    ushort_t* outh  = qkv   + (size_t)MPAD * QKVC;        // MPAD*512

    dim3 blk(256);
    conv_k<<<CONV_BLOCKS, blk, 0, stream>>>(x, wq, wkv, wout, xb, wcatT, woutT);
    gemm_k<false><<<dim3(12, 37), blk, 0, stream>>>(xb, wcatT, nullptr, qkv, QKVC);
    attn_k<<<dim3(NTOK), blk, 0, stream>>>(qkv, wtalk, outh);
    gemm_k<true><<<dim3(4, 37), blk, 0, stream>>>(outh, woutT, bout, out, DIM);
}

// Round 3
// 57.832 us; speedup vs baseline: 3.5308x; 1.5707x over previous
//
#include <hip/hip_runtime.h>
#include <cfloat>
#include <cmath>

#define F_   8
#define H_   24
#define W_   24
#define NTOK 4608
#define NSEQ 4609
#define MPAD 4736           // 37 * 128
#define DIM  512
#define QKVC 1536           // q | k | v
#define NNB  28
#define SCALEF 0.125f

typedef unsigned short ushort_t;
typedef __attribute__((ext_vector_type(8))) short short8v;
typedef __attribute__((ext_vector_type(8))) unsigned short ushort8v;
typedef __attribute__((ext_vector_type(4))) unsigned short ushort4v;
typedef __attribute__((ext_vector_type(4))) float floatx4;

typedef const __attribute__((address_space(1))) unsigned int guint_t;
typedef __attribute__((address_space(3))) unsigned int luint_t;

__device__ __forceinline__ float bf2f(unsigned short u) {
    return __uint_as_float(((unsigned)u) << 16);
}
__device__ __forceinline__ unsigned short f2bf(float f) {
    unsigned u = __float_as_uint(f);
    unsigned r = (u + 0x7FFFu + ((u >> 16) & 1u)) >> 16;
    return (unsigned short)r;
}

// ---------------------------------------------------------------------------
// Fused conversion:
//  blocks [0, XBLK):        x(f32) -> xb(bf16), rows zero-padded to MPAD
//  blocks [XBLK, XBLK+192): [w_q | w_kv] -> wcatT (bf16, [1536][512])
//  blocks [XBLK+192, +64):  w_out -> woutT (bf16, [512][512])
// Transposes go through a 64x64 LDS tile: coalesced float4 reads,
// transposed bf16 LDS writes, coalesced ushort8 stores.
// ---------------------------------------------------------------------------
#define XBLK 1184                      // MPAD*512/2048
#define CONV_BLOCKS (XBLK + 192 + 64)

__global__ __launch_bounds__(256) void conv_k(
    const float* __restrict__ x, const float* __restrict__ wq,
    const float* __restrict__ wkv, const float* __restrict__ wout,
    ushort_t* __restrict__ xb, ushort_t* __restrict__ wcatT,
    ushort_t* __restrict__ woutT)
{
    const int bid = blockIdx.x, tid = threadIdx.x;
    __shared__ ushort_t tile[64][72];   // [n-local][k-local], 16B-aligned rows

    if (bid < XBLK) {
        int e0 = (bid * 256 + tid) * 8;
        int row = e0 >> 9;
        float4 a = make_float4(0.f, 0.f, 0.f, 0.f);
        float4 b = make_float4(0.f, 0.f, 0.f, 0.f);
        if (row < NSEQ) {
            a = *reinterpret_cast<const float4*>(&x[e0]);
            b = *reinterpret_cast<const float4*>(&x[e0 + 4]);
        }
        ushort8v o;
        o[0] = f2bf(a.x); o[1] = f2bf(a.y); o[2] = f2bf(a.z); o[3] = f2bf(a.w);
        o[4] = f2bf(b.x); o[5] = f2bf(b.y); o[6] = f2bf(b.z); o[7] = f2bf(b.w);
        *reinterpret_cast<ushort8v*>(&xb[e0]) = o;
        return;
    }

    int blk2 = bid - XBLK;             // 0..255
    const float* src; int ld, cb; ushort_t* dst; int k0;
    if (blk2 < 192) {
        int nt = blk2 >> 3, kt = blk2 & 7;
        int n0 = nt * 64;
        if (n0 < 512) { src = wq;  ld = 512;  cb = n0; }
        else          { src = wkv; ld = 1024; cb = n0 - 512; }
        dst = wcatT + (size_t)n0 * 512;
        k0 = kt * 64;
    } else {
        int b3 = blk2 - 192;
        int nt = b3 >> 3, kt = b3 & 7;
        src = wout; ld = 512; cb = nt * 64;
        dst = woutT + (size_t)(nt * 64) * 512;
        k0 = kt * 64;
    }

    {
        int r = tid >> 4, c4 = (tid & 15) * 4;
        #pragma unroll
        for (int p = 0; p < 4; ++p) {
            int rr = r + p * 16;
            float4 v = *reinterpret_cast<const float4*>(&src[(size_t)(k0 + rr) * ld + cb + c4]);
            tile[c4 + 0][rr] = f2bf(v.x);
            tile[c4 + 1][rr] = f2bf(v.y);
            tile[c4 + 2][rr] = f2bf(v.z);
            tile[c4 + 3][rr] = f2bf(v.w);
        }
    }
    __syncthreads();
    {
        int nl = tid >> 3, ks = (tid & 7) * 8;
        #pragma unroll
        for (int rep = 0; rep < 2; ++rep) {
            int nn = nl + rep * 32;
            ushort8v vv = *reinterpret_cast<const ushort8v*>(&tile[nn][ks]);
            *reinterpret_cast<ushort8v*>(&dst[(size_t)nn * 512 + k0 + ks]) = vv;
        }
    }
}

// ---------------------------------------------------------------------------
// bf16 MFMA GEMM (unchanged from round 2): 128x128 tile, BK=64, 4 waves,
// 16x16x32 MFMA, global_load_lds width-16, XOR slot swizzle.
// ---------------------------------------------------------------------------
template<bool F32OUT>
__global__ __launch_bounds__(256, 2) void gemm_k(
    const ushort_t* __restrict__ A,    // [MPAD][512] bf16
    const ushort_t* __restrict__ BT,   // [N][512] bf16
    const float* __restrict__ bias,
    void* __restrict__ Cv, int ldc)
{
    __shared__ ushort_t sA[128 * 64];
    __shared__ ushort_t sB[128 * 64];
    const int tid = threadIdx.x;
    const int row0 = blockIdx.y * 128, col0 = blockIdx.x * 128;
    const int wid = tid >> 6, lane = tid & 63;
    const int wr = wid >> 1, wc = wid & 1;
    const int l15 = lane & 15, kp = lane >> 4;

    floatx4 acc[4][4];
    #pragma unroll
    for (int m = 0; m < 4; ++m)
        #pragma unroll
        for (int n = 0; n < 4; ++n)
            acc[m][n] = (floatx4){0.f, 0.f, 0.f, 0.f};

    const ushort_t* Abase = A + (size_t)row0 * 512;
    const ushort_t* Bbase = BT + (size_t)col0 * 512;

    for (int kt = 0; kt < 8; ++kt) {
        const int k0 = kt * 64;
        #pragma unroll
        for (int rnd = 0; rnd < 4; ++rnd) {
            int r = rnd * 32 + (tid >> 3);
            int gs = (tid & 7) ^ (r & 7);
            __builtin_amdgcn_global_load_lds(
                (guint_t*)(Abase + (size_t)r * 512 + k0 + gs * 8),
                (luint_t*)(sA + r * 64 + (tid & 7) * 8), 16, 0, 0);
        }
        #pragma unroll
        for (int rnd = 0; rnd < 4; ++rnd) {
            int r = rnd * 32 + (tid >> 3);
            int gs = (tid & 7) ^ (r & 7);
            __builtin_amdgcn_global_load_lds(
                (guint_t*)(Bbase + (size_t)r * 512 + k0 + gs * 8),
                (luint_t*)(sB + r * 64 + (tid & 7) * 8), 16, 0, 0);
        }
        __syncthreads();

        short8v af[4][2], bfr[4][2];
        #pragma unroll
        for (int m = 0; m < 4; ++m) {
            int r = wr * 64 + m * 16 + l15;
            #pragma unroll
            for (int kk = 0; kk < 2; ++kk) {
                int slot = kk * 4 + kp;
                af[m][kk] = *(const short8v*)&sA[r * 64 + ((slot ^ (r & 7)) << 3)];
            }
        }
        #pragma unroll
        for (int n = 0; n < 4; ++n) {
            int r = wc * 64 + n * 16 + l15;
            #pragma unroll
            for (int kk = 0; kk < 2; ++kk) {
                int slot = kk * 4 + kp;
                bfr[n][kk] = *(const short8v*)&sB[r * 64 + ((slot ^ (r & 7)) << 3)];
            }
        }
        #pragma unroll
        for (int kk = 0; kk < 2; ++kk)
            #pragma unroll
            for (int m = 0; m < 4; ++m)
                #pragma unroll
                for (int n = 0; n < 4; ++n)
                    acc[m][n] = __builtin_amdgcn_mfma_f32_16x16x32_bf16(
                        af[m][kk], bfr[n][kk], acc[m][n], 0, 0, 0);
        __syncthreads();
    }

    if (!F32OUT) {
        ushort_t* C = (ushort_t*)Cv;
        #pragma unroll
        for (int m = 0; m < 4; ++m) {
            int rb = row0 + wr * 64 + m * 16 + kp * 4;
            #pragma unroll
            for (int n = 0; n < 4; ++n) {
                int col = col0 + wc * 64 + n * 16 + l15;
                #pragma unroll
                for (int q = 0; q < 4; ++q)
                    C[(size_t)(rb + q) * ldc + col] = f2bf(acc[m][n][q]);
            }
        }
    } else {
        float* C = (float*)Cv;
        #pragma unroll
        for (int m = 0; m < 4; ++m) {
            int rb = row0 + wr * 64 + m * 16 + kp * 4;
            #pragma unroll
            for (int n = 0; n < 4; ++n) {
                int col = col0 + wc * 64 + n * 16 + l15;
                float bv = bias[col];
                #pragma unroll
                for (int q = 0; q < 4; ++q)
                    if (rb + q < NSEQ)
                        C[(size_t)(rb + q) * ldc + col] = acc[m][n][q] + bv;
            }
        }
    }
}

// ---------------------------------------------------------------------------
// Attention, wave-per-token: 4 waves/block, no LDS, no barriers.
// Lane = (h = lane>>3, s = lane&7). Per lane:
//  - partial 8-wide dots for all 28 neighbors (K loads: 16B/lane, coalesced)
//  - reduce-scatter butterfly (xor 1,2,4 with cndmask selection) so lane s
//    ends with full sims for j = s+8k in STATIC slots k=0..3
//  - group softmax via 3-shfl max/sum
//  - talking-heads via 32 shfl
//  - PV: p broadcast via shfl, 16B V loads, 8 outputs/lane
// ---------------------------------------------------------------------------
__global__ __launch_bounds__(256) void attn_k(
    const ushort_t* __restrict__ qkv,
    const float* __restrict__ wtalk,
    ushort_t* __restrict__ outh)
{
    const int lane = threadIdx.x & 63;
    const int i = blockIdx.x * 4 + (threadIdx.x >> 6);
    const int h = lane >> 3, s = lane & 7;

    const int t = i / (H_ * W_), rem = i % (H_ * W_);
    const int yy = rem / W_, xx = rem % W_;

    // neighbor row for j = lane (lane < 28), else -1
    int rowj = -1;
    if (lane == 0) rowj = 0;
    else if (lane < NNB) {
        int e = lane - 1;
        int dt = e / 9 - 1, dy = (e / 3) % 3 - 1, dx = e % 3 - 1;
        int nt = t + dt, ny = yy + dy, nx = xx + dx;
        bool valid = ((unsigned)nt < (unsigned)F_) && ((unsigned)ny < (unsigned)H_) &&
                     ((unsigned)nx < (unsigned)W_);
        int u = (nt * H_ + ny) * W_ + nx;
        rowj = (valid && u <= i) ? (u + 1) : -1;
    }

    int rows[NNB];
    #pragma unroll
    for (int j = 0; j < NNB; ++j) rows[j] = __shfl(rowj, j, 64);

    // q fragment: q[h][s*8 .. s*8+8] = qkv row i+1, offset lane*8
    float qf[8];
    {
        ushort8v qv = *(const ushort8v*)&qkv[(size_t)(i + 1) * QKVC + lane * 8];
        #pragma unroll
        for (int e = 0; e < 8; ++e) qf[e] = bf2f(qv[e]);
    }

    // partial dots over this lane's d-octet
    float ps[NNB];
    #pragma unroll
    for (int j = 0; j < NNB; ++j) {
        int r = rows[j] < 0 ? 0 : rows[j];
        ushort8v kv = *(const ushort8v*)&qkv[(size_t)r * QKVC + 512 + lane * 8];
        float a = 0.f;
        #pragma unroll
        for (int e = 0; e < 8; ++e) a += qf[e] * bf2f(kv[e]);
        ps[j] = a;
    }

    // reduce-scatter: stage 1 (xor 1) -> 14 vals, j = 2m + (s&1)
    float v1[14];
    {
        bool hi = (s & 1) != 0;
        #pragma unroll
        for (int m = 0; m < 14; ++m) {
            float keep = hi ? ps[2 * m + 1] : ps[2 * m];
            float oth  = hi ? ps[2 * m]     : ps[2 * m + 1];
            v1[m] = keep + __shfl_xor(oth, 1, 64);
        }
    }
    // stage 2 (xor 2) -> 7 vals, j = 4m + (s&3)
    float v2[8];
    {
        bool hi = (s & 2) != 0;
        #pragma unroll
        for (int m = 0; m < 7; ++m) {
            float keep = hi ? v1[2 * m + 1] : v1[2 * m];
            float oth  = hi ? v1[2 * m]     : v1[2 * m + 1];
            v2[m] = keep + __shfl_xor(oth, 2, 64);
        }
        v2[7] = 0.f;
    }
    // stage 3 (xor 4) -> 4 vals, j = s + 8k
    float simk[4];
    {
        bool hi = (s & 4) != 0;
        #pragma unroll
        for (int k = 0; k < 4; ++k) {
            float keep = hi ? v2[2 * k + 1] : v2[2 * k];
            float oth  = hi ? v2[2 * k]     : v2[2 * k + 1];
            simk[k] = keep + __shfl_xor(oth, 4, 64);
        }
    }
    // mask + scale (lanes 28..31 have rowj = -1, so j >= 28 masks naturally)
    #pragma unroll
    for (int k = 0; k < 4; ++k) {
        int j = s + 8 * k;
        int rj = __shfl(rowj, j, 64);
        simk[k] = (rj >= 0) ? simk[k] * SCALEF : -FLT_MAX;
    }

    // group softmax (8 lanes x 4 slots)
    float mx = fmaxf(fmaxf(simk[0], simk[1]), fmaxf(simk[2], simk[3]));
    mx = fmaxf(mx, __shfl_xor(mx, 1, 64));
    mx = fmaxf(mx, __shfl_xor(mx, 2, 64));
    mx = fmaxf(mx, __shfl_xor(mx, 4, 64));
    float att[4];
    float S = 0.f;
    #pragma unroll
    for (int k = 0; k < 4; ++k) { att[k] = __expf(simk[k] - mx); S += att[k]; }
    S += __shfl_xor(S, 1, 64);
    S += __shfl_xor(S, 2, 64);
    S += __shfl_xor(S, 4, 64);
    float inv = 1.f / S;
    #pragma unroll
    for (int k = 0; k < 4; ++k) att[k] *= inv;

    // talking heads: this lane's output head g = h; pk[k] = p[h][s+8k]
    float wtg[8];
    #pragma unroll
    for (int hh = 0; hh < 8; ++hh) wtg[hh] = wtalk[h * 8 + hh];
    float pk[4];
    #pragma unroll
    for (int k = 0; k < 4; ++k) {
        float acc = 0.f;
        #pragma unroll
        for (int hh = 0; hh < 8; ++hh)
            acc += wtg[hh] * __shfl(att[k], hh * 8 + s, 64);
        pk[k] = acc;
    }

    // PV: out[h][s*8 .. +8]
    float o[8];
    #pragma unroll
    for (int e = 0; e < 8; ++e) o[e] = 0.f;
    #pragma unroll
    for (int j = 0; j < NNB; ++j) {
        float pj = __shfl(pk[j >> 3], h * 8 + (j & 7), 64);
        int r = rows[j] < 0 ? 0 : rows[j];
        ushort8v vv = *(const ushort8v*)&qkv[(size_t)r * QKVC + 1024 + lane * 8];
        #pragma unroll
        for (int e = 0; e < 8; ++e) o[e] += pj * bf2f(vv[e]);
    }

    ushort8v ov;
    #pragma unroll
    for (int e = 0; e < 8; ++e) ov[e] = f2bf(o[e]);
    *(ushort8v*)&outh[(size_t)(i + 1) * DIM + lane * 8] = ov;

    if (i == 0) {
        // out row 0 = v row 0
        ushort8v bv = *(const ushort8v*)&qkv[1024 + lane * 8];
        *(ushort8v*)&outh[lane * 8] = bv;
    }
}

extern "C" void kernel_launch(void* const* d_in, const int* in_sizes, int n_in,
                              void* d_out, int out_size, void* d_ws, size_t ws_size,
                              hipStream_t stream) {
    const float* x     = (const float*)d_in[0];
    const float* wq    = (const float*)d_in[1];
    const float* wkv   = (const float*)d_in[2];
    const float* wtalk = (const float*)d_in[3];
    const float* wout  = (const float*)d_in[4];
    const float* bout  = (const float*)d_in[5];
    float* out = (float*)d_out;

    ushort_t* xb    = (ushort_t*)d_ws;                    // MPAD*512 bf16
    ushort_t* wcatT = xb    + (size_t)MPAD * 512;         // 1536*512
    ushort_t* woutT = wcatT + (size_t)QKVC * 512;         // 512*512
    ushort_t* qkv   = woutT + (size_t)512 * 512;          // MPAD*1536
    ushort_t* outh  = qkv   + (size_t)MPAD * QKVC;        // MPAD*512

    dim3 blk(256);
    conv_k<<<CONV_BLOCKS, blk, 0, stream>>>(x, wq, wkv, wout, xb, wcatT, woutT);
    gemm_k<false><<<dim3(12, 37), blk, 0, stream>>>(xb, wcatT, nullptr, qkv, QKVC);
    attn_k<<<dim3(NTOK / 4), blk, 0, stream>>>(qkv, wtalk, outh);
    gemm_k<true><<<dim3(4, 37), blk, 0, stream>>>(outh, woutT, bout, out, DIM);
}

// Round 4
// 53.278 us; speedup vs baseline: 3.8326x; 1.0855x over previous
//
#include <hip/hip_runtime.h>
#include <cfloat>
#include <cmath>

#define F_   8
#define H_   24
#define W_   24
#define NTOK 4608
#define NSEQ 4609
#define MPAD 4736           // 37*128 = 74*64
#define DIM  512
#define QKVC 1536           // q | k | v
#define NNB  28
#define SCALEF 0.125f

typedef unsigned short ushort_t;
typedef __attribute__((ext_vector_type(8))) short short8v;
typedef __attribute__((ext_vector_type(8))) unsigned short ushort8v;
typedef __attribute__((ext_vector_type(4))) unsigned short ushort4v;
typedef __attribute__((ext_vector_type(4))) float floatx4;

typedef const __attribute__((address_space(1))) unsigned int guint_t;
typedef __attribute__((address_space(3))) unsigned int luint_t;

__device__ __forceinline__ float bf2f(unsigned short u) {
    return __uint_as_float(((unsigned)u) << 16);
}
__device__ __forceinline__ unsigned short f2bf(float f) {
    unsigned u = __float_as_uint(f);
    unsigned r = (u + 0x7FFFu + ((u >> 16) & 1u)) >> 16;
    return (unsigned short)r;
}

// ---------------------------------------------------------------------------
// Fused conversion (unchanged from round 3):
//  blocks [0, XBLK):        x(f32) -> xb(bf16), rows zero-padded to MPAD
//  blocks [XBLK, XBLK+192): [w_q | w_kv] -> wcatT (bf16, [1536][512])
//  blocks [XBLK+192, +64):  w_out -> woutT (bf16, [512][512])
// ---------------------------------------------------------------------------
#define XBLK 1184                      // MPAD*512/2048
#define CONV_BLOCKS (XBLK + 192 + 64)

__global__ __launch_bounds__(256) void conv_k(
    const float* __restrict__ x, const float* __restrict__ wq,
    const float* __restrict__ wkv, const float* __restrict__ wout,
    ushort_t* __restrict__ xb, ushort_t* __restrict__ wcatT,
    ushort_t* __restrict__ woutT)
{
    const int bid = blockIdx.x, tid = threadIdx.x;
    __shared__ ushort_t tile[64][72];

    if (bid < XBLK) {
        int e0 = (bid * 256 + tid) * 8;
        int row = e0 >> 9;
        float4 a = make_float4(0.f, 0.f, 0.f, 0.f);
        float4 b = make_float4(0.f, 0.f, 0.f, 0.f);
        if (row < NSEQ) {
            a = *reinterpret_cast<const float4*>(&x[e0]);
            b = *reinterpret_cast<const float4*>(&x[e0 + 4]);
        }
        ushort8v o;
        o[0] = f2bf(a.x); o[1] = f2bf(a.y); o[2] = f2bf(a.z); o[3] = f2bf(a.w);
        o[4] = f2bf(b.x); o[5] = f2bf(b.y); o[6] = f2bf(b.z); o[7] = f2bf(b.w);
        *reinterpret_cast<ushort8v*>(&xb[e0]) = o;
        return;
    }

    int blk2 = bid - XBLK;
    const float* src; int ld, cb; ushort_t* dst; int k0;
    if (blk2 < 192) {
        int nt = blk2 >> 3, kt = blk2 & 7;
        int n0 = nt * 64;
        if (n0 < 512) { src = wq;  ld = 512;  cb = n0; }
        else          { src = wkv; ld = 1024; cb = n0 - 512; }
        dst = wcatT + (size_t)n0 * 512;
        k0 = kt * 64;
    } else {
        int b3 = blk2 - 192;
        int nt = b3 >> 3, kt = b3 & 7;
        src = wout; ld = 512; cb = nt * 64;
        dst = woutT + (size_t)(nt * 64) * 512;
        k0 = kt * 64;
    }

    {
        int r = tid >> 4, c4 = (tid & 15) * 4;
        #pragma unroll
        for (int p = 0; p < 4; ++p) {
            int rr = r + p * 16;
            float4 v = *reinterpret_cast<const float4*>(&src[(size_t)(k0 + rr) * ld + cb + c4]);
            tile[c4 + 0][rr] = f2bf(v.x);
            tile[c4 + 1][rr] = f2bf(v.y);
            tile[c4 + 2][rr] = f2bf(v.z);
            tile[c4 + 3][rr] = f2bf(v.w);
        }
    }
    __syncthreads();
    {
        int nl = tid >> 3, ks = (tid & 7) * 8;
        #pragma unroll
        for (int rep = 0; rep < 2; ++rep) {
            int nn = nl + rep * 32;
            ushort8v vv = *reinterpret_cast<const ushort8v*>(&tile[nn][ks]);
            *reinterpret_cast<ushort8v*>(&dst[(size_t)nn * 512 + k0 + ks]) = vv;
        }
    }
}

// ---------------------------------------------------------------------------
// bf16 MFMA GEMM: C[M x N] = A[M x 512] * B[512 x N], BT[N][512].
// BM x 128 tile (BM = 128 or 64), BK=64, 4 waves, 16x16x32 MFMA.
// global_load_lds width-16 staging, XOR slot swizzle. Per-kk fragment
// loads (32 frag VGPRs) + __launch_bounds__(256,3) -> 3 blocks/CU.
// Bijective XCD-chunked block swizzle (m204).
// ---------------------------------------------------------------------------
template<int BM, bool F32OUT>
__global__ __launch_bounds__(256, 3) void gemm_k(
    const ushort_t* __restrict__ A,    // [MPAD][512] bf16
    const ushort_t* __restrict__ BT,   // [N][512] bf16
    const float* __restrict__ bias,
    void* __restrict__ Cv, int ldc)
{
    __shared__ ushort_t sA[BM * 64];
    __shared__ ushort_t sB[128 * 64];
    const int tid = threadIdx.x;

    // bijective XCD swizzle: contiguous wg-chunks per XCD
    const int nwg = gridDim.x * gridDim.y;
    const int orig = blockIdx.y * gridDim.x + blockIdx.x;
    const int xcd = orig & 7;
    const int qq = nwg >> 3, rr8 = nwg & 7;
    const int wg = (xcd < rr8 ? xcd * (qq + 1) : rr8 * (qq + 1) + (xcd - rr8) * qq)
                   + (orig >> 3);
    const int row0 = (wg / gridDim.x) * BM;
    const int col0 = (wg % gridDim.x) * 128;

    const int wid = tid >> 6, lane = tid & 63;
    const int wr = wid >> 1, wc = wid & 1;
    const int l15 = lane & 15, kp = lane >> 4;
    constexpr int MR = BM / 32;        // m-fragments per wave

    floatx4 acc[MR][4];
    #pragma unroll
    for (int m = 0; m < MR; ++m)
        #pragma unroll
        for (int n = 0; n < 4; ++n)
            acc[m][n] = (floatx4){0.f, 0.f, 0.f, 0.f};

    const ushort_t* Abase = A + (size_t)row0 * 512;
    const ushort_t* Bbase = BT + (size_t)col0 * 512;

    for (int kt = 0; kt < 8; ++kt) {
        const int k0 = kt * 64;
        #pragma unroll
        for (int rnd = 0; rnd < BM / 32; ++rnd) {
            int r = rnd * 32 + (tid >> 3);
            int gs = (tid & 7) ^ (r & 7);
            __builtin_amdgcn_global_load_lds(
                (guint_t*)(Abase + (size_t)r * 512 + k0 + gs * 8),
                (luint_t*)(sA + r * 64 + (tid & 7) * 8), 16, 0, 0);
        }
        #pragma unroll
        for (int rnd = 0; rnd < 4; ++rnd) {
            int r = rnd * 32 + (tid >> 3);
            int gs = (tid & 7) ^ (r & 7);
            __builtin_amdgcn_global_load_lds(
                (guint_t*)(Bbase + (size_t)r * 512 + k0 + gs * 8),
                (luint_t*)(sB + r * 64 + (tid & 7) * 8), 16, 0, 0);
        }
        __syncthreads();

        #pragma unroll
        for (int kk = 0; kk < 2; ++kk) {
            short8v af[MR], bfr[4];
            #pragma unroll
            for (int m = 0; m < MR; ++m) {
                int r = wr * (BM / 2) + m * 16 + l15;
                int slot = kk * 4 + kp;
                af[m] = *(const short8v*)&sA[r * 64 + ((slot ^ (r & 7)) << 3)];
            }
            #pragma unroll
            for (int n = 0; n < 4; ++n) {
                int r = wc * 64 + n * 16 + l15;
                int slot = kk * 4 + kp;
                bfr[n] = *(const short8v*)&sB[r * 64 + ((slot ^ (r & 7)) << 3)];
            }
            #pragma unroll
            for (int m = 0; m < MR; ++m)
                #pragma unroll
                for (int n = 0; n < 4; ++n)
                    acc[m][n] = __builtin_amdgcn_mfma_f32_16x16x32_bf16(
                        af[m], bfr[n], acc[m][n], 0, 0, 0);
        }
        __syncthreads();
    }

    if (!F32OUT) {
        ushort_t* C = (ushort_t*)Cv;
        #pragma unroll
        for (int m = 0; m < MR; ++m) {
            int rb = row0 + wr * (BM / 2) + m * 16 + kp * 4;
            #pragma unroll
            for (int n = 0; n < 4; ++n) {
                int col = col0 + wc * 64 + n * 16 + l15;
                #pragma unroll
                for (int q = 0; q < 4; ++q)
                    C[(size_t)(rb + q) * ldc + col] = f2bf(acc[m][n][q]);
            }
        }
    } else {
        float* C = (float*)Cv;
        #pragma unroll
        for (int m = 0; m < MR; ++m) {
            int rb = row0 + wr * (BM / 2) + m * 16 + kp * 4;
            #pragma unroll
            for (int n = 0; n < 4; ++n) {
                int col = col0 + wc * 64 + n * 16 + l15;
                float bv = bias[col];
                #pragma unroll
                for (int q = 0; q < 4; ++q)
                    if (rb + q < NSEQ)
                        C[(size_t)(rb + q) * ldc + col] = acc[m][n][q] + bv;
            }
        }
    }
}

// ---------------------------------------------------------------------------
// Attention, wave-per-token (unchanged from round 3).
// ---------------------------------------------------------------------------
__global__ __launch_bounds__(256) void attn_k(
    const ushort_t* __restrict__ qkv,
    const float* __restrict__ wtalk,
    ushort_t* __restrict__ outh)
{
    const int lane = threadIdx.x & 63;
    const int i = blockIdx.x * 4 + (threadIdx.x >> 6);
    const int h = lane >> 3, s = lane & 7;

    const int t = i / (H_ * W_), rem = i % (H_ * W_);
    const int yy = rem / W_, xx = rem % W_;

    int rowj = -1;
    if (lane == 0) rowj = 0;
    else if (lane < NNB) {
        int e = lane - 1;
        int dt = e / 9 - 1, dy = (e / 3) % 3 - 1, dx = e % 3 - 1;
        int nt = t + dt, ny = yy + dy, nx = xx + dx;
        bool valid = ((unsigned)nt < (unsigned)F_) && ((unsigned)ny < (unsigned)H_) &&
                     ((unsigned)nx < (unsigned)W_);
        int u = (nt * H_ + ny) * W_ + nx;
        rowj = (valid && u <= i) ? (u + 1) : -1;
    }

    int rows[NNB];
    #pragma unroll
    for (int j = 0; j < NNB; ++j) rows[j] = __shfl(rowj, j, 64);

    float qf[8];
    {
        ushort8v qv = *(const ushort8v*)&qkv[(size_t)(i + 1) * QKVC + lane * 8];
        #pragma unroll
        for (int e = 0; e < 8; ++e) qf[e] = bf2f(qv[e]);
    }

    float ps[NNB];
    #pragma unroll
    for (int j = 0; j < NNB; ++j) {
        int r = rows[j] < 0 ? 0 : rows[j];
        ushort8v kv = *(const ushort8v*)&qkv[(size_t)r * QKVC + 512 + lane * 8];
        float a = 0.f;
        #pragma unroll
        for (int e = 0; e < 8; ++e) a += qf[e] * bf2f(kv[e]);
        ps[j] = a;
    }

    float v1[14];
    {
        bool hi = (s & 1) != 0;
        #pragma unroll
        for (int m = 0; m < 14; ++m) {
            float keep = hi ? ps[2 * m + 1] : ps[2 * m];
            float oth  = hi ? ps[2 * m]     : ps[2 * m + 1];
            v1[m] = keep + __shfl_xor(oth, 1, 64);
        }
    }
    float v2[8];
    {
        bool hi = (s & 2) != 0;
        #pragma unroll
        for (int m = 0; m < 7; ++m) {
            float keep = hi ? v1[2 * m + 1] : v1[2 * m];
            float oth  = hi ? v1[2 * m]     : v1[2 * m + 1];
            v2[m] = keep + __shfl_xor(oth, 2, 64);
        }
        v2[7] = 0.f;
    }
    float simk[4];
    {
        bool hi = (s & 4) != 0;
        #pragma unroll
        for (int k = 0; k < 4; ++k) {
            float keep = hi ? v2[2 * k + 1] : v2[2 * k];
            float oth  = hi ? v2[2 * k]     : v2[2 * k + 1];
            simk[k] = keep + __shfl_xor(oth, 4, 64);
        }
    }
    #pragma unroll
    for (int k = 0; k < 4; ++k) {
        int j = s + 8 * k;
        int rj = __shfl(rowj, j, 64);
        simk[k] = (rj >= 0) ? simk[k] * SCALEF : -FLT_MAX;
    }

    float mx = fmaxf(fmaxf(simk[0], simk[1]), fmaxf(simk[2], simk[3]));
    mx = fmaxf(mx, __shfl_xor(mx, 1, 64));
    mx = fmaxf(mx, __shfl_xor(mx, 2, 64));
    mx = fmaxf(mx, __shfl_xor(mx, 4, 64));
    float att[4];
    float S = 0.f;
    #pragma unroll
    for (int k = 0; k < 4; ++k) { att[k] = __expf(simk[k] - mx); S += att[k]; }
    S += __shfl_xor(S, 1, 64);
    S += __shfl_xor(S, 2, 64);
    S += __shfl_xor(S, 4, 64);
    float inv = 1.f / S;
    #pragma unroll
    for (int k = 0; k < 4; ++k) att[k] *= inv;

    float wtg[8];
    #pragma unroll
    for (int hh = 0; hh < 8; ++hh) wtg[hh] = wtalk[h * 8 + hh];
    float pk[4];
    #pragma unroll
    for (int k = 0; k < 4; ++k) {
        float acc = 0.f;
        #pragma unroll
        for (int hh = 0; hh < 8; ++hh)
            acc += wtg[hh] * __shfl(att[k], hh * 8 + s, 64);
        pk[k] = acc;
    }

    float o[8];
    #pragma unroll
    for (int e = 0; e < 8; ++e) o[e] = 0.f;
    #pragma unroll
    for (int j = 0; j < NNB; ++j) {
        float pj = __shfl(pk[j >> 3], h * 8 + (j & 7), 64);
        int r = rows[j] < 0 ? 0 : rows[j];
        ushort8v vv = *(const ushort8v*)&qkv[(size_t)r * QKVC + 1024 + lane * 8];
        #pragma unroll
        for (int e = 0; e < 8; ++e) o[e] += pj * bf2f(vv[e]);
    }

    ushort8v ov;
    #pragma unroll
    for (int e = 0; e < 8; ++e) ov[e] = f2bf(o[e]);
    *(ushort8v*)&outh[(size_t)(i + 1) * DIM + lane * 8] = ov;

    if (i == 0) {
        ushort8v bv = *(const ushort8v*)&qkv[1024 + lane * 8];
        *(ushort8v*)&outh[lane * 8] = bv;
    }
}

extern "C" void kernel_launch(void* const* d_in, const int* in_sizes, int n_in,
                              void* d_out, int out_size, void* d_ws, size_t ws_size,
                              hipStream_t stream) {
    const float* x     = (const float*)d_in[0];
    const float* wq    = (const float*)d_in[1];
    const float* wkv   = (const float*)d_in[2];
    const float* wtalk = (const float*)d_in[3];
    const float* wout  = (const float*)d_in[4];
    const float* bout  = (const float*)d_in[5];
    float* out = (float*)d_out;

    ushort_t* xb    = (ushort_t*)d_ws;                    // MPAD*512 bf16
    ushort_t* wcatT = xb    + (size_t)MPAD * 512;         // 1536*512
    ushort_t* woutT = wcatT + (size_t)QKVC * 512;         // 512*512
    ushort_t* qkv   = woutT + (size_t)512 * 512;          // MPAD*1536
    ushort_t* outh  = qkv   + (size_t)MPAD * QKVC;        // MPAD*512

    dim3 blk(256);
    conv_k<<<CONV_BLOCKS, blk, 0, stream>>>(x, wq, wkv, wout, xb, wcatT, woutT);
    gemm_k<128, false><<<dim3(12, 37), blk, 0, stream>>>(xb, wcatT, nullptr, qkv, QKVC);
    attn_k<<<dim3(NTOK / 4), blk, 0, stream>>>(qkv, wtalk, outh);
    gemm_k<64, true><<<dim3(4, 74), blk, 0, stream>>>(outh, woutT, bout, out, DIM);
}